// Round 3
// baseline (253.818 us; speedup 1.0000x reference)
//
#include <hip/hip_runtime.h>

// MHA: B=4 T=2048 C=1024 H=16 HD=64, causal, fp32 in/out, bf16 MFMA internally.
// Pipeline: prep(cast+transposes, fused) -> GEMM1(QKV, V transposed, Q pre-scaled)
//           -> flash-attn -> GEMM2.
// R9 = R8 with gemm1 ported to a 256x256 / 8-wave / counted-vmcnt pipelined
// schedule (T3+T4): BK=32, FOUR LDS K-tile buffers (128KB), 3-K-tile prefetch
// lead, steady-state gate = s_waitcnt vmcnt(10) -- the main loop NEVER drains
// vmcnt to 0 (the 2-barrier structure's per-K-step vmcnt(0)+barrier drain is
// its measured ~690 TF ceiling; counted vmcnt is the catalog's +28-41% lever).
// Per-wave k-queue ledger: 4 loads/K-tile/thread; at group g the outstanding
// queue is [kt g(4), g+1(4), g+2(4)] + 2 just-issued -> vmcnt(10) retires kt g.
// Tail groups 29/30/31: vmcnt(8/4/0). attn/gemm2/prep unchanged from R8.

typedef unsigned short u16;
typedef short short8_t __attribute__((ext_vector_type(8)));
typedef float f32x4 __attribute__((ext_vector_type(4)));

#define B_ 4
#define T_ 2048
#define C_ 1024
#define H_ 16
#define HD_ 64
// 0.125 * log2(e): folded into Q at GEMM1 epilogue so attn uses bare exp2.
#define QSCALE 0.18033688011112042f

__device__ __forceinline__ u16 f32_to_bf16(float f) {
  unsigned int u = __float_as_uint(f);
  u += 0x7fffu + ((u >> 16) & 1u);  // RNE
  return (u16)(u >> 16);
}

__device__ __forceinline__ void async_copy16(const void* g, void* l) {
  __builtin_amdgcn_global_load_lds((const __attribute__((address_space(1))) void*)g,
                                   (__attribute__((address_space(3))) void*)l, 16, 0, 0);
}

__device__ __forceinline__ void wave_barrier() { asm volatile("s_barrier" ::: "memory"); }
template <int N>
__device__ __forceinline__ void wait_vmcnt() {
  asm volatile("s_waitcnt vmcnt(%0)" ::"i"(N) : "memory");
}

// ---------------- fused prep: cast x + transpose both weights ----------------
__device__ __forceinline__ void transpose_tile(const float* __restrict__ in,
                                               u16* __restrict__ out, int K, int N, int bx, int by,
                                               float (*tile)[33], int tid) {
  int nb = bx * 32, kb = by * 32;
  int c = tid & 31, r0 = tid >> 5;
#pragma unroll
  for (int rr = 0; rr < 4; ++rr) {
    int r = r0 + rr * 8;
    tile[r][c] = in[(size_t)(kb + r) * N + nb + c];
  }
  __syncthreads();
#pragma unroll
  for (int rr = 0; rr < 4; ++rr) {
    int r = r0 + rr * 8;
    out[(size_t)(nb + r) * K + kb + c] = f32_to_bf16(tile[c][r]);
  }
}

__global__ void prep_kernel(const float* __restrict__ x, u16* __restrict__ Xb,
                            const float* __restrict__ Wqkv, u16* __restrict__ WqkvT,
                            const float* __restrict__ Wproj, u16* __restrict__ WprojT) {
  __shared__ float tile[32][33];
  int id = blockIdx.x;
  int tid = threadIdx.x;
  if (id < 8192) {
    int i = id * 256 + tid;
    float4 v = ((const float4*)x)[i];
    unsigned int a = (unsigned int)f32_to_bf16(v.x) | ((unsigned int)f32_to_bf16(v.y) << 16);
    unsigned int b = (unsigned int)f32_to_bf16(v.z) | ((unsigned int)f32_to_bf16(v.w) << 16);
    ((uint2*)Xb)[i] = make_uint2(a, b);
  } else if (id < 11264) {
    int t = id - 8192;
    transpose_tile(Wqkv, WqkvT, C_, 3 * C_, t % 96, t / 96, tile, tid);
  } else {
    int t = id - 11264;
    transpose_tile(Wproj, WprojT, C_, C_, t % 32, t / 32, tile, tid);
  }
}

// ======================= GEMM1: 256x256 pipelined =======================
// LDS per K-tile buffer (32KB): A half0 [128 rows][32 k] @0, A half1 @8192,
// B half0 @16384, B half1 @24576. Rows 64B; chunk swizzle: phys = log ^ (row&3).
// Staging: linear LDS dest + inverse-swizzled global source (both-sides rule).
__device__ __forceinline__ void g1_stageA(const u16* __restrict__ A, char* dst, int m0, int kt,
                                          int tid) {
  int row = tid >> 2;
  int c = (tid & 3) ^ (row & 3);
  const u16* src = A + (size_t)(m0 + row) * C_ + kt * 32 + c * 8;
  async_copy16(src, dst + tid * 16);
  async_copy16(src + (size_t)128 * C_, dst + 8192 + tid * 16);
}
__device__ __forceinline__ void g1_stageB(const u16* __restrict__ Bt, char* dst, int n0, int kt,
                                          int tid) {
  int row = tid >> 2;
  int c = (tid & 3) ^ (row & 3);
  const u16* src = Bt + (size_t)(n0 + row) * C_ + kt * 32 + c * 8;
  async_copy16(src, dst + 16384 + tid * 16);
  async_copy16(src + (size_t)128 * C_, dst + 24576 + tid * 16);
}

// One K-tile group: reads kt g from buf (g&3); stages kt g+3 into buf ((g+3)&3).
template <bool STAGE, int W>
__device__ __forceinline__ void g1_group(const u16* __restrict__ A, const u16* __restrict__ Bt,
                                         char* smem, int m0, int n0, int g, int tid, int aoff,
                                         int boff, f32x4 (&acc)[8][4]) {
  if (STAGE) g1_stageA(A, smem + ((g + 3) & 3) * 32768, m0, g + 3, tid);
  wait_vmcnt<W>();  // retire kt g's 4 staging loads (per-wave; barrier makes it global)
  wave_barrier();
  char* base = smem + (g & 3) * 32768;
  short8_t af[4], bf[4];
#pragma unroll
  for (int i = 0; i < 4; ++i) af[i] = *(const short8_t*)(base + aoff + i * 1024);
#pragma unroll
  for (int i = 0; i < 4; ++i) bf[i] = *(const short8_t*)(base + boff + i * 1024);
  __builtin_amdgcn_s_setprio(1);
#pragma unroll
  for (int mt = 0; mt < 4; ++mt)
#pragma unroll
    for (int nt = 0; nt < 4; ++nt)
      acc[mt][nt] = __builtin_amdgcn_mfma_f32_16x16x32_bf16(af[mt], bf[nt], acc[mt][nt], 0, 0, 0);
  __builtin_amdgcn_s_setprio(0);
  if (STAGE) g1_stageB(Bt, smem + ((g + 3) & 3) * 32768, n0, g + 3, tid);
#pragma unroll
  for (int i = 0; i < 4; ++i) af[i] = *(const short8_t*)(base + aoff + 4096 + i * 1024);
  __builtin_amdgcn_s_setprio(1);
#pragma unroll
  for (int mt = 0; mt < 4; ++mt)
#pragma unroll
    for (int nt = 0; nt < 4; ++nt)
      acc[4 + mt][nt] =
          __builtin_amdgcn_mfma_f32_16x16x32_bf16(af[mt], bf[nt], acc[4 + mt][nt], 0, 0, 0);
  __builtin_amdgcn_s_setprio(0);
  wave_barrier();
}

// X[8192x1024] @ WqkvT[3072x1024] -> Q,K [B,H,T,HD]; V [B,H,HD,T].
// Grid 12x32 (n-tile, m-tile), 512 threads = 8 waves (2M x 4N), wave owns 128x64.
__global__ __launch_bounds__(512, 2) void gemm1_kernel(const u16* __restrict__ A,
                                                       const u16* __restrict__ Bt,
                                                       const float* __restrict__ bias,
                                                       u16* __restrict__ Qo, u16* __restrict__ Ko,
                                                       u16* __restrict__ Vo) {
  __shared__ __align__(128) char smem[131072];
  int tid = threadIdx.x;
  int lane = tid & 63, wave = tid >> 6;
  int quad = lane >> 4, l15 = lane & 15;
  int waveM = wave >> 2, waveN = wave & 3;
  int m0 = blockIdx.y * 256, n0 = blockIdx.x * 256;

  f32x4 acc[8][4];
#pragma unroll
  for (int mt = 0; mt < 8; ++mt)
#pragma unroll
    for (int nt = 0; nt < 4; ++nt) acc[mt][nt] = (f32x4){0.f, 0.f, 0.f, 0.f};

  // per-lane LDS read offsets (swizzle chunk = quad ^ (l15&3), rows are 64B)
  int swz = (quad ^ (l15 & 3)) << 4;
  int aoff = waveM * 8192 + l15 * 64 + swz;
  int boff = 16384 + (waveN >> 1) * 8192 + (waveN & 1) * 4096 + l15 * 64 + swz;

  // prologue: stage kt 0,1,2 (12 loads/thread); retire kt0 (leave 8 in flight)
  g1_stageA(A, smem, m0, 0, tid);
  g1_stageB(Bt, smem, n0, 0, tid);
  g1_stageA(A, smem + 32768, m0, 1, tid);
  g1_stageB(Bt, smem + 32768, n0, 1, tid);
  g1_stageA(A, smem + 65536, m0, 2, tid);
  g1_stageB(Bt, smem + 65536, n0, 2, tid);
  wait_vmcnt<8>();
  wave_barrier();

#pragma unroll 4
  for (int g = 0; g < 29; ++g) g1_group<true, 10>(A, Bt, smem, m0, n0, g, tid, aoff, boff, acc);
  g1_group<false, 8>(A, Bt, smem, m0, n0, 29, tid, aoff, boff, acc);
  g1_group<false, 4>(A, Bt, smem, m0, n0, 30, tid, aoff, boff, acc);
  g1_group<false, 0>(A, Bt, smem, m0, n0, 31, tid, aoff, boff, acc);

  // ---- epilogue ----
  int nb = n0 + waveN * 64;
  if (n0 < 2048) {
    // Q/K: direct scalar stores; Q pre-scaled by QSCALE
#pragma unroll
    for (int nt = 0; nt < 4; ++nt) {
      int n = nb + nt * 16;
      int which = n >> 10;
      int rem = n & 1023;
      int head = rem >> 6;
      int d = (rem & 63) + l15;
      float bv = bias[n + l15];
      float sc = (which == 0) ? QSCALE : 1.0f;
      u16* dst = (which == 0) ? Qo : Ko;
#pragma unroll
      for (int mt = 0; mt < 8; ++mt) {
#pragma unroll
        for (int r = 0; r < 4; ++r) {
          int token = m0 + waveM * 128 + mt * 16 + quad * 4 + r;
          int b = token >> 11, t = token & 2047;
          dst[(((size_t)(b * H_ + head)) * T_ + t) * HD_ + d] =
              f32_to_bf16((acc[mt][nt][r] + bv) * sc);
        }
      }
    }
  } else {
    // V: transpose wave's 64(n) x 128(m) block through LDS, 64x64 at a time
    char* W = smem + wave * 8192;  // [d-local 64 rows][128B], 16B chunks XOR-swizzled
    int b = m0 >> 11;
#pragma unroll
    for (int mh = 0; mh < 2; ++mh) {
#pragma unroll
      for (int nt = 0; nt < 4; ++nt) {
        int nl = nt * 16 + l15;
        float bv = bias[nb + nl];
#pragma unroll
        for (int mtp = 0; mtp < 4; ++mtp) {
          int mt = mh * 4 + mtp;
          int g = mtp * 4 + quad;              // 8B granule (4 tokens)
          int pc = ((g >> 1) ^ (nl & 7)) & 7;  // swizzled 16B chunk
          uint2 pv;
          pv.x = (unsigned int)f32_to_bf16(acc[mt][nt][0] + bv) |
                 ((unsigned int)f32_to_bf16(acc[mt][nt][1] + bv) << 16);
          pv.y = (unsigned int)f32_to_bf16(acc[mt][nt][2] + bv) |
                 ((unsigned int)f32_to_bf16(acc[mt][nt][3] + bv) << 16);
          *(uint2*)(W + nl * 128 + pc * 16 + (g & 1) * 8) = pv;
        }
      }
#pragma unroll
      for (int i = 0; i < 8; ++i) {
        int jj = i * 64 + lane;
        int nl = jj >> 3;  // d-local row
        int c = jj & 7;    // logical 16B chunk = tokens c*8..c*8+7
        int pc = c ^ (nl & 7);
        uint4 v = *(const uint4*)(W + nl * 128 + pc * 16);
        int rem = (nb - 2048) + nl;
        int head = rem >> 6, dd = rem & 63;
        int t0 = (m0 & 2047) + waveM * 128 + mh * 64 + c * 8;
        *(uint4*)(Vo + ((size_t)(b * H_ + head) * HD_ + dd) * T_ + t0) = v;
      }
    }
  }
}

// ---------------- shared 128x128 GEMM mainloop (gemm2) ----------------
__device__ __forceinline__ void stage_tile(const u16* __restrict__ A, const u16* __restrict__ Bt,
                                           int K, int m0, int n0, int k0, char* buf, int tid) {
#pragma unroll
  for (int it = 0; it < 2; ++it) {
    int j = it * 256 + tid;
    int row = j >> 2;
    int ch = ((j & 3) ^ (row >> 1)) & 3;
    async_copy16(A + (size_t)(m0 + row) * K + k0 + ch * 8, buf + j * 16);
    async_copy16(Bt + (size_t)(n0 + row) * K + k0 + ch * 8, buf + 8192 + j * 16);
  }
}

__device__ __forceinline__ void gemm_mainloop(const u16* __restrict__ A, const u16* __restrict__ Bt,
                                              int K, int m0, int n0, char* smem,
                                              f32x4 (&acc)[4][4]) {
  int tid = threadIdx.x;
  int lane = tid & 63, wave = tid >> 6;
  int quad = lane >> 4, l15 = lane & 15;
  int waveM = wave >> 1, waveN = wave & 1;
  stage_tile(A, Bt, K, m0, n0, 0, smem, tid);
  int nIter = K >> 5;
  for (int ki = 0; ki < nIter; ++ki) {
    int cur = ki & 1;
    char* bufc = smem + cur * 16384;
    __syncthreads();  // publishes buf[cur] (loads issued a full iter ago)
    if (ki + 1 < nIter)
      stage_tile(A, Bt, K, m0, n0, (ki + 1) << 5, smem + (cur ^ 1) * 16384, tid);
    short8_t af[4], bfr[4];
#pragma unroll
    for (int mt = 0; mt < 4; ++mt) {
      int row = waveM * 64 + mt * 16 + l15;
      af[mt] = *(const short8_t*)(bufc + row * 64 + (((quad ^ (row >> 1)) & 3) << 4));
    }
#pragma unroll
    for (int nt = 0; nt < 4; ++nt) {
      int row = waveN * 64 + nt * 16 + l15;
      bfr[nt] = *(const short8_t*)(bufc + 8192 + row * 64 + (((quad ^ (row >> 1)) & 3) << 4));
    }
#pragma unroll
    for (int mt = 0; mt < 4; ++mt)
#pragma unroll
      for (int nt = 0; nt < 4; ++nt)
        acc[mt][nt] = __builtin_amdgcn_mfma_f32_16x16x32_bf16(af[mt], bfr[nt], acc[mt][nt], 0, 0, 0);
  }
}

// -------- GEMM2: Y[8192x1024] @ WprojT + bproj -> out fp32 --------
__global__ __launch_bounds__(256, 2) void gemm2_kernel(const u16* __restrict__ A,
                                                       const u16* __restrict__ Bt,
                                                       const float* __restrict__ bias,
                                                       float* __restrict__ out) {
  __shared__ __align__(128) char smem[32768];
  f32x4 acc[4][4];
#pragma unroll
  for (int mt = 0; mt < 4; ++mt)
#pragma unroll
    for (int nt = 0; nt < 4; ++nt) acc[mt][nt] = (f32x4){0.f, 0.f, 0.f, 0.f};
  int m0 = blockIdx.y * 128, n0 = blockIdx.x * 128;
  gemm_mainloop(A, Bt, C_, m0, n0, smem, acc);

  int lane = threadIdx.x & 63, wave = threadIdx.x >> 6;
  int quad = lane >> 4, l15 = lane & 15;
  int waveM = wave >> 1, waveN = wave & 1;
#pragma unroll
  for (int nt = 0; nt < 4; ++nt) {
    int col = n0 + waveN * 64 + nt * 16 + l15;
    float bv = bias[col];
#pragma unroll
    for (int mt = 0; mt < 4; ++mt) {
#pragma unroll
      for (int r = 0; r < 4; ++r) {
        int token = m0 + waveM * 64 + mt * 16 + quad * 4 + r;
        out[(size_t)token * C_ + col] = acc[mt][nt][r] + bv;
      }
    }
  }
}

// -------- flash attention: Q-tile 128 (4 waves x 32 rows), K-tile 64 --------
__device__ __forceinline__ void stage_kv(const u16* __restrict__ Kb, const u16* __restrict__ Vb,
                                         int kt, char* Ksb, char* Vsb, int tid) {
#pragma unroll
  for (int it = 0; it < 2; ++it) {
    int j = it * 256 + tid;
    int row = j >> 3;
    int ch = (j & 7) ^ (row & 7);
    async_copy16(Kb + (size_t)(kt * 64 + row) * HD_ + ch * 8, Ksb + j * 16);
    async_copy16(Vb + (size_t)row * T_ + kt * 64 + ch * 8, Vsb + j * 16);
  }
}

__global__ __launch_bounds__(256, 3) void attn_kernel(const u16* __restrict__ Qg,
                                                      const u16* __restrict__ Kg,
                                                      const u16* __restrict__ Vg,
                                                      u16* __restrict__ Yg) {
  __shared__ __align__(128) char smem[49152];
  int tid = threadIdx.x;
  int wave = tid >> 6, lane = tid & 63;
  int quad = lane >> 4, l15 = lane & 15;
  char* Psw = smem + 32768 + wave * 4096;  // wave-private 32x64 bf16
  int bh = blockIdx.x;
  int qt = 15 - blockIdx.y;  // heaviest blocks dispatch first (x-major)
  int b = bh >> 4, h = bh & 15;
  const u16* Kb = Kg + (size_t)bh * T_ * HD_;
  const u16* Vb = Vg + (size_t)bh * HD_ * T_;

  short8_t qf[2][2];  // [mt][ks]
#pragma unroll
  for (int mt = 0; mt < 2; ++mt)
#pragma unroll
    for (int ks = 0; ks < 2; ++ks) {
      int row = qt * 128 + wave * 32 + mt * 16 + l15;
      qf[mt][ks] = *(const short8_t*)(Qg + ((size_t)bh * T_ + row) * HD_ + ks * 32 + quad * 8);
    }

  stage_kv(Kb, Vb, 0, smem, smem + 16384, tid);  // prefetch tile 0

  float l_part[2][4];
  f32x4 o[2][4];
#pragma unroll
  for (int mt = 0; mt < 2; ++mt)
#pragma unroll
    for (int r = 0; r < 4; ++r) l_part[mt][r] = 0.f;
#pragma unroll
  for (int mt = 0; mt < 2; ++mt)
#pragma unroll
    for (int dt = 0; dt < 4; ++dt) o[mt][dt] = (f32x4){0.f, 0.f, 0.f, 0.f};

  int ktmax_blk = 2 * qt + 1;
  int ktmax_wave = 2 * qt + (wave >> 1);
  for (int kt = 0; kt <= ktmax_blk; ++kt) {
    int cur = kt & 1;
    char* Ksc = smem + cur * 8192;
    char* Vtc = smem + 16384 + cur * 8192;
    __syncthreads();
    if (kt < ktmax_blk)
      stage_kv(Kb, Vb, kt + 1, smem + (cur ^ 1) * 8192, smem + 16384 + (cur ^ 1) * 8192, tid);
    if (kt > ktmax_wave) continue;

    f32x4 s[2][4];
#pragma unroll
    for (int mt = 0; mt < 2; ++mt)
#pragma unroll
      for (int nt = 0; nt < 4; ++nt) s[mt][nt] = (f32x4){0.f, 0.f, 0.f, 0.f};
#pragma unroll
    for (int ks = 0; ks < 2; ++ks) {
      short8_t bfr[4];
#pragma unroll
      for (int nt = 0; nt < 4; ++nt) {
        int row = nt * 16 + l15;
        bfr[nt] = *(const short8_t*)(Ksc + row * 128 + ((((ks * 4 + quad) ^ row) & 7) << 4));
      }
#pragma unroll
      for (int mt = 0; mt < 2; ++mt)
#pragma unroll
        for (int nt = 0; nt < 4; ++nt)
          s[mt][nt] =
              __builtin_amdgcn_mfma_f32_16x16x32_bf16(qf[mt][ks], bfr[nt], s[mt][nt], 0, 0, 0);
    }

    if (kt == ktmax_wave) {  // masked diagonal tile (once per wave)
#pragma unroll
      for (int mt = 0; mt < 2; ++mt) {
        int qrow0 = qt * 128 + wave * 32 + mt * 16 + quad * 4;
#pragma unroll
        for (int nt = 0; nt < 4; ++nt) {
          int col = kt * 64 + nt * 16 + l15;
#pragma unroll
          for (int r = 0; r < 4; ++r) {
            float p = __builtin_amdgcn_exp2f(s[mt][nt][r]);
            if (col > qrow0 + r) p = 0.f;
            s[mt][nt][r] = p;
          }
        }
      }
    } else {
#pragma unroll
      for (int mt = 0; mt < 2; ++mt)
#pragma unroll
        for (int nt = 0; nt < 4; ++nt)
#pragma unroll
          for (int r = 0; r < 4; ++r) s[mt][nt][r] = __builtin_amdgcn_exp2f(s[mt][nt][r]);
    }

#pragma unroll
    for (int mt = 0; mt < 2; ++mt) {
#pragma unroll
      for (int r = 0; r < 4; ++r)
        l_part[mt][r] += (s[mt][0][r] + s[mt][1][r]) + (s[mt][2][r] + s[mt][3][r]);
#pragma unroll
      for (int nt = 0; nt < 4; ++nt) {
        int col = nt * 16 + l15;
#pragma unroll
        for (int r = 0; r < 4; ++r) {
          int prow = mt * 16 + quad * 4 + r;
          *(u16*)(Psw + prow * 128 + ((((col >> 3) ^ prow) & 7) << 4) + ((col & 7) << 1)) =
              (u16)(__float_as_uint(s[mt][nt][r]) >> 16);
        }
      }
    }

#pragma unroll
    for (int ks = 0; ks < 2; ++ks) {
      short8_t af[2], bfr[4];
#pragma unroll
      for (int mt = 0; mt < 2; ++mt) {
        int row = mt * 16 + l15;
        af[mt] = *(const short8_t*)(Psw + row * 128 + ((((ks * 4 + quad) ^ row) & 7) << 4));
      }
#pragma unroll
      for (int dt = 0; dt < 4; ++dt) {
        int row = dt * 16 + l15;
        bfr[dt] = *(const short8_t*)(Vtc + row * 128 + ((((ks * 4 + quad) ^ row) & 7) << 4));
      }
#pragma unroll
      for (int mt = 0; mt < 2; ++mt)
#pragma unroll
        for (int dt = 0; dt < 4; ++dt)
          o[mt][dt] = __builtin_amdgcn_mfma_f32_16x16x32_bf16(af[mt], bfr[dt], o[mt][dt], 0, 0, 0);
    }
  }

#pragma unroll
  for (int mt = 0; mt < 2; ++mt) {
#pragma unroll
    for (int r = 0; r < 4; ++r) {
      float lsum = l_part[mt][r];
#pragma unroll
      for (int off = 1; off < 16; off <<= 1) lsum += __shfl_xor(lsum, off);
      float inv = 1.0f / lsum;
#pragma unroll
      for (int dt = 0; dt < 4; ++dt) {
        int t = qt * 128 + wave * 32 + mt * 16 + quad * 4 + r;
        float val = o[mt][dt][r] * inv;
        Yg[((size_t)(b * T_ + t)) * C_ + h * HD_ + dt * 16 + l15] = f32_to_bf16(val);
      }
    }
  }
}

extern "C" void kernel_launch(void* const* d_in, const int* in_sizes, int n_in,
                              void* d_out, int out_size, void* d_ws, size_t ws_size,
                              hipStream_t stream) {
  (void)in_sizes; (void)n_in; (void)out_size; (void)ws_size;
  const float* x = (const float*)d_in[0];
  const float* Wqkv = (const float*)d_in[1];
  const float* bqkv = (const float*)d_in[2];
  const float* Wproj = (const float*)d_in[3];
  const float* bproj = (const float*)d_in[4];
  float* out = (float*)d_out;
  char* ws = (char*)d_ws;

  // workspace layout (75.5 MB total):
  u16* Xb = (u16*)ws;                             // 16.78 MB, reused as Y after GEMM1
  u16* WqkvT = (u16*)(ws + 16777216);             //  6.29 MB  [3072][1024]
  u16* WprojT = (u16*)(ws + 16777216 + 6291456);  //  2.10 MB  [1024][1024]
  u16* Q = (u16*)(ws + 25165824);                 // 16.78 MB  [B,H,T,HD] (pre-scaled)
  u16* K = Q + 8388608;                           // 16.78 MB  [B,H,T,HD]
  u16* V = K + 8388608;                           // 16.78 MB  [B,H,HD,T]
  u16* Y = Xb;  // alias: Xb dead after GEMM1

  prep_kernel<<<12288, 256, 0, stream>>>(x, Xb, Wqkv, WqkvT, Wproj, WprojT);
  gemm1_kernel<<<dim3(12, 32), 512, 0, stream>>>(Xb, WqkvT, bqkv, Q, K, V);
  attn_kernel<<<dim3(64, 16), 256, 0, stream>>>(Q, K, V, Y);
  gemm2_kernel<<<dim3(8, 64), 256, 0, stream>>>(Y, WprojT, bproj, out);
}

// Round 4
// 235.459 us; speedup vs baseline: 1.0780x; 1.0780x over previous
//
#include <hip/hip_runtime.h>

// MHA: B=4 T=2048 C=1024 H=16 HD=64, causal, fp32 in/out, bf16 MFMA internally.
// Pipeline: prep(cast+transposes, fused) -> GEMM1(QKV, V transposed, Q pre-scaled)
//           -> flash-attn -> GEMM2.
// R10 = R9 with the gemm1 LDS swizzle FIXED: R9 XOR'd chunks with (row&3),
// which is constant across l15∈{0,4,8,12} within a quarter-wave -> 4-way bank
// conflict on every fragment read (measured: SQ_LDS_BANK_CONFLICT 131K->4.85M,
// MfmaUtil stuck at 27%). Correct spreading is (row>>1)&3 (the R8 kernel's
// idiom): per 16-lane sub-pass each 4-bank group then gets exactly 2 lanes
// (2-way = free). Fixed on BOTH sides of the involution (staging source chunk
// + fragment-read chunk). Everything else identical to R9.

typedef unsigned short u16;
typedef short short8_t __attribute__((ext_vector_type(8)));
typedef float f32x4 __attribute__((ext_vector_type(4)));

#define B_ 4
#define T_ 2048
#define C_ 1024
#define H_ 16
#define HD_ 64
// 0.125 * log2(e): folded into Q at GEMM1 epilogue so attn uses bare exp2.
#define QSCALE 0.18033688011112042f

__device__ __forceinline__ u16 f32_to_bf16(float f) {
  unsigned int u = __float_as_uint(f);
  u += 0x7fffu + ((u >> 16) & 1u);  // RNE
  return (u16)(u >> 16);
}

__device__ __forceinline__ void async_copy16(const void* g, void* l) {
  __builtin_amdgcn_global_load_lds((const __attribute__((address_space(1))) void*)g,
                                   (__attribute__((address_space(3))) void*)l, 16, 0, 0);
}

__device__ __forceinline__ void wave_barrier() { asm volatile("s_barrier" ::: "memory"); }
template <int N>
__device__ __forceinline__ void wait_vmcnt() {
  asm volatile("s_waitcnt vmcnt(%0)" ::"i"(N) : "memory");
}

// ---------------- fused prep: cast x + transpose both weights ----------------
__device__ __forceinline__ void transpose_tile(const float* __restrict__ in,
                                               u16* __restrict__ out, int K, int N, int bx, int by,
                                               float (*tile)[33], int tid) {
  int nb = bx * 32, kb = by * 32;
  int c = tid & 31, r0 = tid >> 5;
#pragma unroll
  for (int rr = 0; rr < 4; ++rr) {
    int r = r0 + rr * 8;
    tile[r][c] = in[(size_t)(kb + r) * N + nb + c];
  }
  __syncthreads();
#pragma unroll
  for (int rr = 0; rr < 4; ++rr) {
    int r = r0 + rr * 8;
    out[(size_t)(nb + r) * K + kb + c] = f32_to_bf16(tile[c][r]);
  }
}

__global__ void prep_kernel(const float* __restrict__ x, u16* __restrict__ Xb,
                            const float* __restrict__ Wqkv, u16* __restrict__ WqkvT,
                            const float* __restrict__ Wproj, u16* __restrict__ WprojT) {
  __shared__ float tile[32][33];
  int id = blockIdx.x;
  int tid = threadIdx.x;
  if (id < 8192) {
    int i = id * 256 + tid;
    float4 v = ((const float4*)x)[i];
    unsigned int a = (unsigned int)f32_to_bf16(v.x) | ((unsigned int)f32_to_bf16(v.y) << 16);
    unsigned int b = (unsigned int)f32_to_bf16(v.z) | ((unsigned int)f32_to_bf16(v.w) << 16);
    ((uint2*)Xb)[i] = make_uint2(a, b);
  } else if (id < 11264) {
    int t = id - 8192;
    transpose_tile(Wqkv, WqkvT, C_, 3 * C_, t % 96, t / 96, tile, tid);
  } else {
    int t = id - 11264;
    transpose_tile(Wproj, WprojT, C_, C_, t % 32, t / 32, tile, tid);
  }
}

// ======================= GEMM1: 256x256 pipelined =======================
// LDS per K-tile buffer (32KB): A half0 [128 rows][32 k] @0, A half1 @8192,
// B half0 @16384, B half1 @24576. Rows 64B; chunk swizzle: phys = log ^ ((row>>1)&3).
// Staging: linear LDS dest + inverse-swizzled global source (both-sides rule).
__device__ __forceinline__ void g1_stageA(const u16* __restrict__ A, char* dst, int m0, int kt,
                                          int tid) {
  int row = tid >> 2;
  int c = (tid & 3) ^ ((row >> 1) & 3);
  const u16* src = A + (size_t)(m0 + row) * C_ + kt * 32 + c * 8;
  async_copy16(src, dst + tid * 16);
  async_copy16(src + (size_t)128 * C_, dst + 8192 + tid * 16);
}
__device__ __forceinline__ void g1_stageB(const u16* __restrict__ Bt, char* dst, int n0, int kt,
                                          int tid) {
  int row = tid >> 2;
  int c = (tid & 3) ^ ((row >> 1) & 3);
  const u16* src = Bt + (size_t)(n0 + row) * C_ + kt * 32 + c * 8;
  async_copy16(src, dst + 16384 + tid * 16);
  async_copy16(src + (size_t)128 * C_, dst + 24576 + tid * 16);
}

// One K-tile group: reads kt g from buf (g&3); stages kt g+3 into buf ((g+3)&3).
template <bool STAGE, int W>
__device__ __forceinline__ void g1_group(const u16* __restrict__ A, const u16* __restrict__ Bt,
                                         char* smem, int m0, int n0, int g, int tid, int aoff,
                                         int boff, f32x4 (&acc)[8][4]) {
  if (STAGE) g1_stageA(A, smem + ((g + 3) & 3) * 32768, m0, g + 3, tid);
  wait_vmcnt<W>();  // retire kt g's 4 staging loads (per-wave; barrier makes it global)
  wave_barrier();
  char* base = smem + (g & 3) * 32768;
  short8_t af[4], bf[4];
#pragma unroll
  for (int i = 0; i < 4; ++i) af[i] = *(const short8_t*)(base + aoff + i * 1024);
#pragma unroll
  for (int i = 0; i < 4; ++i) bf[i] = *(const short8_t*)(base + boff + i * 1024);
  __builtin_amdgcn_s_setprio(1);
#pragma unroll
  for (int mt = 0; mt < 4; ++mt)
#pragma unroll
    for (int nt = 0; nt < 4; ++nt)
      acc[mt][nt] = __builtin_amdgcn_mfma_f32_16x16x32_bf16(af[mt], bf[nt], acc[mt][nt], 0, 0, 0);
  __builtin_amdgcn_s_setprio(0);
  if (STAGE) g1_stageB(Bt, smem + ((g + 3) & 3) * 32768, n0, g + 3, tid);
#pragma unroll
  for (int i = 0; i < 4; ++i) af[i] = *(const short8_t*)(base + aoff + 4096 + i * 1024);
  __builtin_amdgcn_s_setprio(1);
#pragma unroll
  for (int mt = 0; mt < 4; ++mt)
#pragma unroll
    for (int nt = 0; nt < 4; ++nt)
      acc[4 + mt][nt] =
          __builtin_amdgcn_mfma_f32_16x16x32_bf16(af[mt], bf[nt], acc[4 + mt][nt], 0, 0, 0);
  __builtin_amdgcn_s_setprio(0);
  wave_barrier();
}

// X[8192x1024] @ WqkvT[3072x1024] -> Q,K [B,H,T,HD]; V [B,H,HD,T].
// Grid 12x32 (n-tile, m-tile), 512 threads = 8 waves (2M x 4N), wave owns 128x64.
__global__ __launch_bounds__(512, 2) void gemm1_kernel(const u16* __restrict__ A,
                                                       const u16* __restrict__ Bt,
                                                       const float* __restrict__ bias,
                                                       u16* __restrict__ Qo, u16* __restrict__ Ko,
                                                       u16* __restrict__ Vo) {
  __shared__ __align__(128) char smem[131072];
  int tid = threadIdx.x;
  int lane = tid & 63, wave = tid >> 6;
  int quad = lane >> 4, l15 = lane & 15;
  int waveM = wave >> 2, waveN = wave & 3;
  int m0 = blockIdx.y * 256, n0 = blockIdx.x * 256;

  f32x4 acc[8][4];
#pragma unroll
  for (int mt = 0; mt < 8; ++mt)
#pragma unroll
    for (int nt = 0; nt < 4; ++nt) acc[mt][nt] = (f32x4){0.f, 0.f, 0.f, 0.f};

  // per-lane LDS read offsets (swizzle chunk = quad ^ ((l15>>1)&3), rows are 64B)
  int swz = (quad ^ ((l15 >> 1) & 3)) << 4;
  int aoff = waveM * 8192 + l15 * 64 + swz;
  int boff = 16384 + (waveN >> 1) * 8192 + (waveN & 1) * 4096 + l15 * 64 + swz;

  // prologue: stage kt 0,1,2 (12 loads/thread); retire kt0 (leave 8 in flight)
  g1_stageA(A, smem, m0, 0, tid);
  g1_stageB(Bt, smem, n0, 0, tid);
  g1_stageA(A, smem + 32768, m0, 1, tid);
  g1_stageB(Bt, smem + 32768, n0, 1, tid);
  g1_stageA(A, smem + 65536, m0, 2, tid);
  g1_stageB(Bt, smem + 65536, n0, 2, tid);
  wait_vmcnt<8>();
  wave_barrier();

#pragma unroll 4
  for (int g = 0; g < 29; ++g) g1_group<true, 10>(A, Bt, smem, m0, n0, g, tid, aoff, boff, acc);
  g1_group<false, 8>(A, Bt, smem, m0, n0, 29, tid, aoff, boff, acc);
  g1_group<false, 4>(A, Bt, smem, m0, n0, 30, tid, aoff, boff, acc);
  g1_group<false, 0>(A, Bt, smem, m0, n0, 31, tid, aoff, boff, acc);

  // ---- epilogue ----
  int nb = n0 + waveN * 64;
  if (n0 < 2048) {
    // Q/K: direct scalar stores; Q pre-scaled by QSCALE
#pragma unroll
    for (int nt = 0; nt < 4; ++nt) {
      int n = nb + nt * 16;
      int which = n >> 10;
      int rem = n & 1023;
      int head = rem >> 6;
      int d = (rem & 63) + l15;
      float bv = bias[n + l15];
      float sc = (which == 0) ? QSCALE : 1.0f;
      u16* dst = (which == 0) ? Qo : Ko;
#pragma unroll
      for (int mt = 0; mt < 8; ++mt) {
#pragma unroll
        for (int r = 0; r < 4; ++r) {
          int token = m0 + waveM * 128 + mt * 16 + quad * 4 + r;
          int b = token >> 11, t = token & 2047;
          dst[(((size_t)(b * H_ + head)) * T_ + t) * HD_ + d] =
              f32_to_bf16((acc[mt][nt][r] + bv) * sc);
        }
      }
    }
  } else {
    // V: transpose wave's 64(n) x 128(m) block through LDS, 64x64 at a time
    char* W = smem + wave * 8192;  // [d-local 64 rows][128B], 16B chunks XOR-swizzled
    int b = m0 >> 11;
#pragma unroll
    for (int mh = 0; mh < 2; ++mh) {
#pragma unroll
      for (int nt = 0; nt < 4; ++nt) {
        int nl = nt * 16 + l15;
        float bv = bias[nb + nl];
#pragma unroll
        for (int mtp = 0; mtp < 4; ++mtp) {
          int mt = mh * 4 + mtp;
          int g = mtp * 4 + quad;              // 8B granule (4 tokens)
          int pc = ((g >> 1) ^ (nl & 7)) & 7;  // swizzled 16B chunk
          uint2 pv;
          pv.x = (unsigned int)f32_to_bf16(acc[mt][nt][0] + bv) |
                 ((unsigned int)f32_to_bf16(acc[mt][nt][1] + bv) << 16);
          pv.y = (unsigned int)f32_to_bf16(acc[mt][nt][2] + bv) |
                 ((unsigned int)f32_to_bf16(acc[mt][nt][3] + bv) << 16);
          *(uint2*)(W + nl * 128 + pc * 16 + (g & 1) * 8) = pv;
        }
      }
#pragma unroll
      for (int i = 0; i < 8; ++i) {
        int jj = i * 64 + lane;
        int nl = jj >> 3;  // d-local row
        int c = jj & 7;    // logical 16B chunk = tokens c*8..c*8+7
        int pc = c ^ (nl & 7);
        uint4 v = *(const uint4*)(W + nl * 128 + pc * 16);
        int rem = (nb - 2048) + nl;
        int head = rem >> 6, dd = rem & 63;
        int t0 = (m0 & 2047) + waveM * 128 + mh * 64 + c * 8;
        *(uint4*)(Vo + ((size_t)(b * H_ + head) * HD_ + dd) * T_ + t0) = v;
      }
    }
  }
}

// ---------------- shared 128x128 GEMM mainloop (gemm2) ----------------
__device__ __forceinline__ void stage_tile(const u16* __restrict__ A, const u16* __restrict__ Bt,
                                           int K, int m0, int n0, int k0, char* buf, int tid) {
#pragma unroll
  for (int it = 0; it < 2; ++it) {
    int j = it * 256 + tid;
    int row = j >> 2;
    int ch = ((j & 3) ^ (row >> 1)) & 3;
    async_copy16(A + (size_t)(m0 + row) * K + k0 + ch * 8, buf + j * 16);
    async_copy16(Bt + (size_t)(n0 + row) * K + k0 + ch * 8, buf + 8192 + j * 16);
  }
}

__device__ __forceinline__ void gemm_mainloop(const u16* __restrict__ A, const u16* __restrict__ Bt,
                                              int K, int m0, int n0, char* smem,
                                              f32x4 (&acc)[4][4]) {
  int tid = threadIdx.x;
  int lane = tid & 63, wave = tid >> 6;
  int quad = lane >> 4, l15 = lane & 15;
  int waveM = wave >> 1, waveN = wave & 1;
  stage_tile(A, Bt, K, m0, n0, 0, smem, tid);
  int nIter = K >> 5;
  for (int ki = 0; ki < nIter; ++ki) {
    int cur = ki & 1;
    char* bufc = smem + cur * 16384;
    __syncthreads();  // publishes buf[cur] (loads issued a full iter ago)
    if (ki + 1 < nIter)
      stage_tile(A, Bt, K, m0, n0, (ki + 1) << 5, smem + (cur ^ 1) * 16384, tid);
    short8_t af[4], bfr[4];
#pragma unroll
    for (int mt = 0; mt < 4; ++mt) {
      int row = waveM * 64 + mt * 16 + l15;
      af[mt] = *(const short8_t*)(bufc + row * 64 + (((quad ^ (row >> 1)) & 3) << 4));
    }
#pragma unroll
    for (int nt = 0; nt < 4; ++nt) {
      int row = waveN * 64 + nt * 16 + l15;
      bfr[nt] = *(const short8_t*)(bufc + 8192 + row * 64 + (((quad ^ (row >> 1)) & 3) << 4));
    }
#pragma unroll
    for (int mt = 0; mt < 4; ++mt)
#pragma unroll
      for (int nt = 0; nt < 4; ++nt)
        acc[mt][nt] = __builtin_amdgcn_mfma_f32_16x16x32_bf16(af[mt], bfr[nt], acc[mt][nt], 0, 0, 0);
  }
}

// -------- GEMM2: Y[8192x1024] @ WprojT + bproj -> out fp32 --------
__global__ __launch_bounds__(256, 2) void gemm2_kernel(const u16* __restrict__ A,
                                                       const u16* __restrict__ Bt,
                                                       const float* __restrict__ bias,
                                                       float* __restrict__ out) {
  __shared__ __align__(128) char smem[32768];
  f32x4 acc[4][4];
#pragma unroll
  for (int mt = 0; mt < 4; ++mt)
#pragma unroll
    for (int nt = 0; nt < 4; ++nt) acc[mt][nt] = (f32x4){0.f, 0.f, 0.f, 0.f};
  int m0 = blockIdx.y * 128, n0 = blockIdx.x * 128;
  gemm_mainloop(A, Bt, C_, m0, n0, smem, acc);

  int lane = threadIdx.x & 63, wave = threadIdx.x >> 6;
  int quad = lane >> 4, l15 = lane & 15;
  int waveM = wave >> 1, waveN = wave & 1;
#pragma unroll
  for (int nt = 0; nt < 4; ++nt) {
    int col = n0 + waveN * 64 + nt * 16 + l15;
    float bv = bias[col];
#pragma unroll
    for (int mt = 0; mt < 4; ++mt) {
#pragma unroll
      for (int r = 0; r < 4; ++r) {
        int token = m0 + waveM * 64 + mt * 16 + quad * 4 + r;
        out[(size_t)token * C_ + col] = acc[mt][nt][r] + bv;
      }
    }
  }
}

// -------- flash attention: Q-tile 128 (4 waves x 32 rows), K-tile 64 --------
__device__ __forceinline__ void stage_kv(const u16* __restrict__ Kb, const u16* __restrict__ Vb,
                                         int kt, char* Ksb, char* Vsb, int tid) {
#pragma unroll
  for (int it = 0; it < 2; ++it) {
    int j = it * 256 + tid;
    int row = j >> 3;
    int ch = (j & 7) ^ (row & 7);
    async_copy16(Kb + (size_t)(kt * 64 + row) * HD_ + ch * 8, Ksb + j * 16);
    async_copy16(Vb + (size_t)row * T_ + kt * 64 + ch * 8, Vsb + j * 16);
  }
}

__global__ __launch_bounds__(256, 3) void attn_kernel(const u16* __restrict__ Qg,
                                                      const u16* __restrict__ Kg,
                                                      const u16* __restrict__ Vg,
                                                      u16* __restrict__ Yg) {
  __shared__ __align__(128) char smem[49152];
  int tid = threadIdx.x;
  int wave = tid >> 6, lane = tid & 63;
  int quad = lane >> 4, l15 = lane & 15;
  char* Psw = smem + 32768 + wave * 4096;  // wave-private 32x64 bf16
  int bh = blockIdx.x;
  int qt = 15 - blockIdx.y;  // heaviest blocks dispatch first (x-major)
  int b = bh >> 4, h = bh & 15;
  const u16* Kb = Kg + (size_t)bh * T_ * HD_;
  const u16* Vb = Vg + (size_t)bh * HD_ * T_;

  short8_t qf[2][2];  // [mt][ks]
#pragma unroll
  for (int mt = 0; mt < 2; ++mt)
#pragma unroll
    for (int ks = 0; ks < 2; ++ks) {
      int row = qt * 128 + wave * 32 + mt * 16 + l15;
      qf[mt][ks] = *(const short8_t*)(Qg + ((size_t)bh * T_ + row) * HD_ + ks * 32 + quad * 8);
    }

  stage_kv(Kb, Vb, 0, smem, smem + 16384, tid);  // prefetch tile 0

  float l_part[2][4];
  f32x4 o[2][4];
#pragma unroll
  for (int mt = 0; mt < 2; ++mt)
#pragma unroll
    for (int r = 0; r < 4; ++r) l_part[mt][r] = 0.f;
#pragma unroll
  for (int mt = 0; mt < 2; ++mt)
#pragma unroll
    for (int dt = 0; dt < 4; ++dt) o[mt][dt] = (f32x4){0.f, 0.f, 0.f, 0.f};

  int ktmax_blk = 2 * qt + 1;
  int ktmax_wave = 2 * qt + (wave >> 1);
  for (int kt = 0; kt <= ktmax_blk; ++kt) {
    int cur = kt & 1;
    char* Ksc = smem + cur * 8192;
    char* Vtc = smem + 16384 + cur * 8192;
    __syncthreads();
    if (kt < ktmax_blk)
      stage_kv(Kb, Vb, kt + 1, smem + (cur ^ 1) * 8192, smem + 16384 + (cur ^ 1) * 8192, tid);
    if (kt > ktmax_wave) continue;

    f32x4 s[2][4];
#pragma unroll
    for (int mt = 0; mt < 2; ++mt)
#pragma unroll
      for (int nt = 0; nt < 4; ++nt) s[mt][nt] = (f32x4){0.f, 0.f, 0.f, 0.f};
#pragma unroll
    for (int ks = 0; ks < 2; ++ks) {
      short8_t bfr[4];
#pragma unroll
      for (int nt = 0; nt < 4; ++nt) {
        int row = nt * 16 + l15;
        bfr[nt] = *(const short8_t*)(Ksc + row * 128 + ((((ks * 4 + quad) ^ row) & 7) << 4));
      }
#pragma unroll
      for (int mt = 0; mt < 2; ++mt)
#pragma unroll
        for (int nt = 0; nt < 4; ++nt)
          s[mt][nt] =
              __builtin_amdgcn_mfma_f32_16x16x32_bf16(qf[mt][ks], bfr[nt], s[mt][nt], 0, 0, 0);
    }

    if (kt == ktmax_wave) {  // masked diagonal tile (once per wave)
#pragma unroll
      for (int mt = 0; mt < 2; ++mt) {
        int qrow0 = qt * 128 + wave * 32 + mt * 16 + quad * 4;
#pragma unroll
        for (int nt = 0; nt < 4; ++nt) {
          int col = kt * 64 + nt * 16 + l15;
#pragma unroll
          for (int r = 0; r < 4; ++r) {
            float p = __builtin_amdgcn_exp2f(s[mt][nt][r]);
            if (col > qrow0 + r) p = 0.f;
            s[mt][nt][r] = p;
          }
        }
      }
    } else {
#pragma unroll
      for (int mt = 0; mt < 2; ++mt)
#pragma unroll
        for (int nt = 0; nt < 4; ++nt)
#pragma unroll
          for (int r = 0; r < 4; ++r) s[mt][nt][r] = __builtin_amdgcn_exp2f(s[mt][nt][r]);
    }

#pragma unroll
    for (int mt = 0; mt < 2; ++mt) {
#pragma unroll
      for (int r = 0; r < 4; ++r)
        l_part[mt][r] += (s[mt][0][r] + s[mt][1][r]) + (s[mt][2][r] + s[mt][3][r]);
#pragma unroll
      for (int nt = 0; nt < 4; ++nt) {
        int col = nt * 16 + l15;
#pragma unroll
        for (int r = 0; r < 4; ++r) {
          int prow = mt * 16 + quad * 4 + r;
          *(u16*)(Psw + prow * 128 + ((((col >> 3) ^ prow) & 7) << 4) + ((col & 7) << 1)) =
              (u16)(__float_as_uint(s[mt][nt][r]) >> 16);
        }
      }
    }

#pragma unroll
    for (int ks = 0; ks < 2; ++ks) {
      short8_t af[2], bfr[4];
#pragma unroll
      for (int mt = 0; mt < 2; ++mt) {
        int row = mt * 16 + l15;
        af[mt] = *(const short8_t*)(Psw + row * 128 + ((((ks * 4 + quad) ^ row) & 7) << 4));
      }
#pragma unroll
      for (int dt = 0; dt < 4; ++dt) {
        int row = dt * 16 + l15;
        bfr[dt] = *(const short8_t*)(Vtc + row * 128 + ((((ks * 4 + quad) ^ row) & 7) << 4));
      }
#pragma unroll
      for (int mt = 0; mt < 2; ++mt)
#pragma unroll
        for (int dt = 0; dt < 4; ++dt)
          o[mt][dt] = __builtin_amdgcn_mfma_f32_16x16x32_bf16(af[mt], bfr[dt], o[mt][dt], 0, 0, 0);
    }
  }

#pragma unroll
  for (int mt = 0; mt < 2; ++mt) {
#pragma unroll
    for (int r = 0; r < 4; ++r) {
      float lsum = l_part[mt][r];
#pragma unroll
      for (int off = 1; off < 16; off <<= 1) lsum += __shfl_xor(lsum, off);
      float inv = 1.0f / lsum;
#pragma unroll
      for (int dt = 0; dt < 4; ++dt) {
        int t = qt * 128 + wave * 32 + mt * 16 + quad * 4 + r;
        float val = o[mt][dt][r] * inv;
        Yg[((size_t)(b * T_ + t)) * C_ + h * HD_ + dt * 16 + l15] = f32_to_bf16(val);
      }
    }
  }
}

extern "C" void kernel_launch(void* const* d_in, const int* in_sizes, int n_in,
                              void* d_out, int out_size, void* d_ws, size_t ws_size,
                              hipStream_t stream) {
  (void)in_sizes; (void)n_in; (void)out_size; (void)ws_size;
  const float* x = (const float*)d_in[0];
  const float* Wqkv = (const float*)d_in[1];
  const float* bqkv = (const float*)d_in[2];
  const float* Wproj = (const float*)d_in[3];
  const float* bproj = (const float*)d_in[4];
  float* out = (float*)d_out;
  char* ws = (char*)d_ws;

  // workspace layout (75.5 MB total):
  u16* Xb = (u16*)ws;                             // 16.78 MB, reused as Y after GEMM1
  u16* WqkvT = (u16*)(ws + 16777216);             //  6.29 MB  [3072][1024]
  u16* WprojT = (u16*)(ws + 16777216 + 6291456);  //  2.10 MB  [1024][1024]
  u16* Q = (u16*)(ws + 25165824);                 // 16.78 MB  [B,H,T,HD] (pre-scaled)
  u16* K = Q + 8388608;                           // 16.78 MB  [B,H,T,HD]
  u16* V = K + 8388608;                           // 16.78 MB  [B,H,HD,T]
  u16* Y = Xb;  // alias: Xb dead after GEMM1

  prep_kernel<<<12288, 256, 0, stream>>>(x, Xb, Wqkv, WqkvT, Wproj, WprojT);
  gemm1_kernel<<<dim3(12, 32), 512, 0, stream>>>(Xb, WqkvT, bqkv, Q, K, V);
  attn_kernel<<<dim3(64, 16), 256, 0, stream>>>(Q, K, V, Y);
  gemm2_kernel<<<dim3(8, 64), 256, 0, stream>>>(Y, WprojT, bproj, out);
}